// Round 5
// baseline (2248.981 us; speedup 1.0000x reference)
//
#include <hip/hip_runtime.h>

// K-means assignment via split-fp16 MFMA GEMM + fused argmin.
// d2 = x2 + c2 - 2*x.cT ; x = hi+lo (fp16 each), dot = hh + hl + lh on
// mfma_f32_16x16x32_f16 (fp32 accum). Error ~1e-6 < fp32 sum-order noise.
// N=131072, K=2048, D=512.
//
// R5 (vs 859us best = R2): NO-LDS register-direct main loop.
//   R2/R4 analysis: LDS demand (~2300cy/period) saturates right where the
//   matrix pipe would become the bound, and the 2-buffer barrier structure
//   (lgkm(0) + s_barrier x2 per K-step) forbids in-wave read/MFMA overlap.
//   LDS staging only bought 2x intra-block reuse -- not worth the sync.
//   New loop: fragments are loaded DIRECTLY from the pre-converted hi/lo
//   planes into registers. Frag addr (row*512 + dt*32 + q*8): the 4 quads
//   of each 16-lane group cover 4x16B contiguous => one coalesced
//   global_load_dwordx4 per frag (16 rows x 64B, full cachelines). The 2x
//   duplicate reads across waves dedupe in L1/L2.
//   iter t: { load frags(t+1) -> alternate reg set; 48 MFMA on frags(t) }.
//   ZERO barriers / explicit waitcnt in the loop; compiler pipelines the
//   loads one MFMA cluster (~1000cy) ahead via per-register vmcnt.
//   Epilogue overlaps the next kt's in-flight loads for free.
// Carried: identical numerics (same 3-term MFMA order), fused argmin,
// lexicographic tie-break => absmax 0 preserved.

#define N_PTS 131072
#define K_CL  2048
#define D_DIM 512
#define BM 128
#define BN 128
#define BK 32
#define NKT (K_CL / BN)    // 16 K-tiles
#define NDT (D_DIM / BK)   // 16 D-steps
#define NT  (NKT * NDT)    // 256 total iterations

typedef _Float16 half8  __attribute__((ext_vector_type(8)));
typedef _Float16 half4v __attribute__((ext_vector_type(4)));
typedef float    floatx4 __attribute__((ext_vector_type(4)));

// ---- c2 norms: one wave per row ----
__global__ void row_norms_kernel(const float* __restrict__ A,
                                 float* __restrict__ out, int rows) {
    int gid  = blockIdx.x * blockDim.x + threadIdx.x;
    int wave = gid >> 6;
    int lane = gid & 63;
    if (wave >= rows) return;
    const float4* a = (const float4*)(A + (size_t)wave * D_DIM);
    float4 p = a[lane];
    float4 q = a[lane + 64];
    float s = p.x*p.x + p.y*p.y + p.z*p.z + p.w*p.w
            + q.x*q.x + q.y*q.y + q.z*q.z + q.w*q.w;
    #pragma unroll
    for (int off = 32; off > 0; off >>= 1) s += __shfl_down(s, off, 64);
    if (lane == 0) out[wave] = s;
}

// ---- fp32 -> (hi,lo) fp16 planes ----
__global__ void conv_f16x2_kernel(const float* __restrict__ src,
                                  _Float16* __restrict__ hi,
                                  _Float16* __restrict__ lo, int n4) {
    int i = blockIdx.x * blockDim.x + threadIdx.x;
    if (i >= n4) return;
    float4 v = ((const float4*)src)[i];
    half4v h, l;
    h.x = (_Float16)v.x; h.y = (_Float16)v.y;
    h.z = (_Float16)v.z; h.w = (_Float16)v.w;
    l.x = (_Float16)(v.x - (float)h.x);
    l.y = (_Float16)(v.y - (float)h.y);
    l.z = (_Float16)(v.z - (float)h.z);
    l.w = (_Float16)(v.w - (float)h.w);
    *(half4v*)(hi + (size_t)i * 4) = h;
    *(half4v*)(lo + (size_t)i * 4) = l;
}

// fp32 float8 -> (hi,lo) half8 in-register (fallback paths)
#define CVT8(H_, L_, U_, V_) do {                                   \
    half8 h_, l_;                                                   \
    h_[0] = (_Float16)(U_).x; l_[0] = (_Float16)((U_).x - (float)h_[0]); \
    h_[1] = (_Float16)(U_).y; l_[1] = (_Float16)((U_).y - (float)h_[1]); \
    h_[2] = (_Float16)(U_).z; l_[2] = (_Float16)((U_).z - (float)h_[2]); \
    h_[3] = (_Float16)(U_).w; l_[3] = (_Float16)((U_).w - (float)h_[3]); \
    h_[4] = (_Float16)(V_).x; l_[4] = (_Float16)((V_).x - (float)h_[4]); \
    h_[5] = (_Float16)(V_).y; l_[5] = (_Float16)((V_).y - (float)h_[5]); \
    h_[6] = (_Float16)(V_).z; l_[6] = (_Float16)((V_).z - (float)h_[6]); \
    h_[7] = (_Float16)(V_).w; l_[7] = (_Float16)((V_).w - (float)h_[7]); \
    (H_) = h_; (L_) = l_;                                           \
} while (0)

// ---- main: 128x128 block over all K, register-direct frags, fused argmin ----
template<bool XPRE, bool CPRE>
__global__ __launch_bounds__(256, 2)
void kmeans_mfma(const float* __restrict__ X, const float* __restrict__ C,
                 const _Float16* __restrict__ Xhi, const _Float16* __restrict__ Xlo,
                 const _Float16* __restrict__ Chi, const _Float16* __restrict__ Clo,
                 const float* __restrict__ c2g, int* __restrict__ out) {
    __shared__ float c2s[K_CL];      // 8 KB (also reduce scratch at the end)
    __shared__ float x2s[BM];        // 0.5 KB
    __shared__ float sred[256];      // x2 partials scratch

    const int tid  = threadIdx.x;
    const int lane = tid & 63;
    const int w    = tid >> 6;       // wave id 0..3
    const int wti  = w >> 1;         // row half
    const int wtj  = w & 1;          // col half
    const int q    = lane >> 4;      // quad
    const int m16  = lane & 15;
    const int rowBase = blockIdx.x * BM;

    // c2 into LDS
    if (CPRE) {
        for (int i = tid; i < K_CL / 4; i += 256)
            ((float4*)c2s)[i] = ((const float4*)c2g)[i];
    } else {
        for (int k = tid; k < K_CL; k += 256) {
            const float4* cp = (const float4*)(C + (size_t)k * D_DIM);
            float s0 = 0.f, s1 = 0.f;
            for (int j = 0; j < D_DIM / 4; j += 2) {
                float4 a = cp[j], b = cp[j + 1];
                s0 += a.x*a.x + a.y*a.y + a.z*a.z + a.w*a.w;
                s1 += b.x*b.x + b.y*b.y + b.z*b.z + b.w*b.w;
            }
            c2s[k] = s0 + s1;
        }
    }
    // x2 into LDS (2 threads per row)
    {
        int r = tid & 127, h = tid >> 7;
        const float4* xp = (const float4*)(X + (size_t)(rowBase + r) * D_DIM + h * 256);
        float s0 = 0.f, s1 = 0.f;
        for (int j = 0; j < 64; j += 2) {
            float4 a = xp[j], b = xp[j + 1];
            s0 += a.x*a.x + a.y*a.y + a.z*a.z + a.w*a.w;
            s1 += b.x*b.x + b.y*b.y + b.z*b.z + b.w*b.w;
        }
        sred[tid] = s0 + s1;
    }
    __syncthreads();
    if (tid < BM) x2s[tid] = sred[tid] + sred[tid + 128];
    __syncthreads();

    // fragment base offsets (uint32 element offsets; uniform plane base stays
    // in SGPR -> saddr-form loads, near-zero per-iter address VALU)
    const uint32_t aoffBase = (uint32_t)(rowBase + wti * 64 + m16) * D_DIM + q * 8;
    const uint32_t boffBase = (uint32_t)(wtj * 64 + m16) * D_DIM + q * 8;

    // two register fragment sets (set index is a LITERAL -- rule #20)
    half8 fah[2][4], fal[2][4], fbh[2][4], fbl[2][4];
    floatx4 acc[4][4];

    // load all 16 frags of tile T_ into set S_ (A: rows fixed, dt varies;
    // B: (kt,tj) cols, dt varies)
    #define LOADF(S_, T_) do {                                             \
        const int t_   = (T_);                                             \
        const int dtl_ = t_ & (NDT - 1);                                   \
        const int ktl_ = t_ >> 4;                                          \
        const uint32_t ao_ = aoffBase + (uint32_t)dtl_ * BK;               \
        const uint32_t bo_ = boffBase + (uint32_t)(ktl_ * BN) * D_DIM      \
                                      + (uint32_t)dtl_ * BK;               \
        _Pragma("unroll")                                                  \
        for (int ti_ = 0; ti_ < 4; ++ti_) {                                \
            const uint32_t o_ = ao_ + ti_ * 16 * D_DIM;                    \
            if constexpr (XPRE) {                                          \
                fah[S_][ti_] = *(const half8*)&Xhi[o_];                    \
                fal[S_][ti_] = *(const half8*)&Xlo[o_];                    \
            } else {                                                       \
                float4 u_ = *(const float4*)&X[o_];                        \
                float4 v_ = *(const float4*)&X[o_ + 4];                    \
                CVT8(fah[S_][ti_], fal[S_][ti_], u_, v_);                  \
            }                                                              \
        }                                                                  \
        _Pragma("unroll")                                                  \
        for (int tj_ = 0; tj_ < 4; ++tj_) {                                \
            const uint32_t o_ = bo_ + tj_ * 16 * D_DIM;                    \
            if constexpr (CPRE) {                                          \
                fbh[S_][tj_] = *(const half8*)&Chi[o_];                    \
                fbl[S_][tj_] = *(const half8*)&Clo[o_];                    \
            } else {                                                       \
                float4 u_ = *(const float4*)&C[o_];                        \
                float4 v_ = *(const float4*)&C[o_ + 4];                    \
                CVT8(fbh[S_][tj_], fbl[S_][tj_], u_, v_);                  \
            }                                                              \
        }                                                                  \
    } while (0)

    #define MFMA48(S_) do {                                                \
        __builtin_amdgcn_s_setprio(1);                                     \
        _Pragma("unroll")                                                  \
        for (int tj_ = 0; tj_ < 4; ++tj_)                                  \
            _Pragma("unroll")                                              \
            for (int ti_ = 0; ti_ < 4; ++ti_) {                            \
                floatx4 a_ = acc[ti_][tj_];                                \
                a_ = __builtin_amdgcn_mfma_f32_16x16x32_f16(fah[S_][ti_], fbh[S_][tj_], a_, 0, 0, 0); \
                a_ = __builtin_amdgcn_mfma_f32_16x16x32_f16(fah[S_][ti_], fbl[S_][tj_], a_, 0, 0, 0); \
                a_ = __builtin_amdgcn_mfma_f32_16x16x32_f16(fal[S_][ti_], fbh[S_][tj_], a_, 0, 0, 0); \
                acc[ti_][tj_] = a_;                                        \
            }                                                              \
        __builtin_amdgcn_s_setprio(0);                                     \
    } while (0)

    float bestV[4][4];
    int   bestI[4][4];
    #pragma unroll
    for (int ti = 0; ti < 4; ++ti)
        #pragma unroll
        for (int r = 0; r < 4; ++r) { bestV[ti][r] = 3.4e38f; bestI[ti][r] = 0; }

    LOADF(0, 0);

    #pragma unroll 1
    for (int kt = 0; kt < NKT; ++kt) {
        const int k0 = kt * BN;
        #pragma unroll
        for (int ti = 0; ti < 4; ++ti)
            #pragma unroll
            for (int tj = 0; tj < 4; ++tj) acc[ti][tj] = (floatx4){0.f, 0.f, 0.f, 0.f};

        #pragma unroll 1
        for (int dt = 0; dt < NDT; dt += 2) {
            const int t = kt * NDT + dt;
            if (t + 1 < NT) LOADF(1, t + 1);   // prefetch under MFMA(t)
            MFMA48(0);
            if (t + 2 < NT) LOADF(0, t + 2);   // prefetch under MFMA(t+1)
            MFMA48(1);
        }

        // fused argmin epilogue. D layout: col=lane&15, row=quad*4+reg.
        // cols ascend (kt, then tj) per (ti,reg) + strict '<'  => first-occurrence.
        // (next kt's frag loads remain in flight underneath this)
        #pragma unroll
        for (int tj = 0; tj < 4; ++tj) {
            int col = k0 + wtj * 64 + tj * 16 + m16;
            float cv = c2s[col];
            #pragma unroll
            for (int ti = 0; ti < 4; ++ti)
                #pragma unroll
                for (int r = 0; r < 4; ++r) {
                    float s = x2s[wti * 64 + ti * 16 + q * 4 + r] + cv;
                    float v = s - 2.0f * acc[ti][tj][r];
                    if (v < bestV[ti][r]) { bestV[ti][r] = v; bestI[ti][r] = col; }
                }
        }
    }
    #undef MFMA48
    #undef LOADF

    // cross-lane reduce over the 16 lanes sharing each row (lexicographic)
    #pragma unroll
    for (int ti = 0; ti < 4; ++ti)
        #pragma unroll
        for (int r = 0; r < 4; ++r) {
            float v = bestV[ti][r]; int ix = bestI[ti][r];
            #pragma unroll
            for (int off = 1; off < 16; off <<= 1) {
                float ov = __shfl_xor(v, off, 64);
                int   oi = __shfl_xor(ix, off, 64);
                if (ov < v || (ov == v && oi < ix)) { v = ov; ix = oi; }
            }
            bestV[ti][r] = v; bestI[ti][r] = ix;
        }

    __syncthreads();                   // c2s no longer needed; reuse as scratch
    float* rv  = c2s;                  // [128][2] floats
    int*   rix = (int*)(c2s + 1024);   // [128][2] ints
    if (m16 == 0) {
        #pragma unroll
        for (int ti = 0; ti < 4; ++ti)
            #pragma unroll
            for (int r = 0; r < 4; ++r) {
                int rloc = wti * 64 + ti * 16 + q * 4 + r;
                rv[rloc * 2 + wtj]  = bestV[ti][r];
                rix[rloc * 2 + wtj] = bestI[ti][r];
            }
    }
    __syncthreads();
    if (tid < BM) {
        float v0 = rv[tid * 2], v1 = rv[tid * 2 + 1];
        int   i0 = rix[tid * 2], i1 = rix[tid * 2 + 1];
        out[rowBase + tid] = (v1 < v0 || (v1 == v0 && i1 < i0)) ? i1 : i0;
    }
}

extern "C" void kernel_launch(void* const* d_in, const int* in_sizes, int n_in,
                              void* d_out, int out_size, void* d_ws, size_t ws_size,
                              hipStream_t stream) {
    const float* X = (const float*)d_in[0];   // [N, D]
    const float* C = (const float*)d_in[1];   // [K, D]
    int* out = (int*)d_out;

    char* ws = (char*)d_ws;
    const size_t c2_off  = 0;
    const size_t chi_off = (size_t)K_CL * 4;                       // 8 KB
    const size_t clo_off = chi_off + (size_t)K_CL * D_DIM * 2;     // +2 MB
    const size_t xhi_off = clo_off + (size_t)K_CL * D_DIM * 2;     // +2 MB
    const size_t xlo_off = xhi_off + (size_t)N_PTS * D_DIM * 2;    // +128 MB
    const size_t need_C    = xhi_off;                              // ~4.2 MB
    const size_t need_full = xlo_off + (size_t)N_PTS * D_DIM * 2;  // ~272.6 MB

    if (ws_size >= need_full) {
        float*    c2  = (float*)(ws + c2_off);
        _Float16* Chi = (_Float16*)(ws + chi_off);
        _Float16* Clo = (_Float16*)(ws + clo_off);
        _Float16* Xhi = (_Float16*)(ws + xhi_off);
        _Float16* Xlo = (_Float16*)(ws + xlo_off);
        row_norms_kernel<<<(K_CL * 64) / 256, 256, 0, stream>>>(C, c2, K_CL);
        conv_f16x2_kernel<<<(K_CL * D_DIM / 4) / 256, 256, 0, stream>>>(
            C, Chi, Clo, K_CL * D_DIM / 4);
        conv_f16x2_kernel<<<(N_PTS * D_DIM / 4 + 255) / 256, 256, 0, stream>>>(
            X, Xhi, Xlo, N_PTS * D_DIM / 4);
        kmeans_mfma<true, true><<<N_PTS / BM, 256, 0, stream>>>(
            X, C, Xhi, Xlo, Chi, Clo, c2, out);
    } else if (ws_size >= need_C) {
        float*    c2  = (float*)(ws + c2_off);
        _Float16* Chi = (_Float16*)(ws + chi_off);
        _Float16* Clo = (_Float16*)(ws + clo_off);
        row_norms_kernel<<<(K_CL * 64) / 256, 256, 0, stream>>>(C, c2, K_CL);
        conv_f16x2_kernel<<<(K_CL * D_DIM / 4) / 256, 256, 0, stream>>>(
            C, Chi, Clo, K_CL * D_DIM / 4);
        kmeans_mfma<false, true><<<N_PTS / BM, 256, 0, stream>>>(
            X, C, nullptr, nullptr, Chi, Clo, c2, out);
    } else {
        kmeans_mfma<false, false><<<N_PTS / BM, 256, 0, stream>>>(
            X, C, nullptr, nullptr, nullptr, nullptr, nullptr, out);
    }
}

// Round 6
// 1597.695 us; speedup vs baseline: 1.4076x; 1.4076x over previous
//
#include <hip/hip_runtime.h>

// K-means assignment via split-fp16 MFMA GEMM + fused argmin.
// d2 = x2 + c2 - 2*x.cT ; x = hi+lo (fp16 each), dot = hh + hl + lh on
// mfma_f32_16x16x32_f16 (fp32 accum). Error ~1e-6 < fp32 sum-order noise.
// N=131072, K=2048, D=512.
//
// R6 = R2 (best, 859us/46%) + ONE change: TRIPLE-buffered LDS -> the
// mid-iteration barrier disappears.
//   R2 iter: reads -> lgkm(0)+bar1 -> stage(t+2) -> MFMA -> vmcnt(8)+bar2.
//   bar1 only existed because stage(t+2) with 2 buffers overwrites the buffer
//   being read. With 3 buffers stage(t+2) -> buf[(t+2)%3], disjoint from the
//   read buffer buf[t%3] and resident buf[(t+1)%3]; its last readers were at
//   iter t-1, ordered by that iter's closing barrier. New iter:
//     { reads(t) ; stage(t+2) ; MFMA(t) [compiler lgkm deps] ;
//       vmcnt(8) counted ; s_barrier }            -- ONE barrier per K-step.
//   Cross-wave safety: each wave's vmcnt(8) before the barrier retires its
//   stage(t+1) GLLs, so when any wave passes the barrier every wave's tile
//   t+1 is resident (same pattern as the 8-phase template).
//   LDS 3x24KB=72KB; c2 moved OUT of LDS (epilogue reads c2g from global,
//   L1/L2-cached, 64 loads/thread total) to stay <=80KB => 2 blocks/CU
//   (R4 showed 1 block/CU destroys the cross-block anti-phase overlap).
// Carried from R2: XOR-swizzled LDS (bank conflicts 0), counted vmcnt
// (never drain-to-0 mid-loop), setprio around MFMA, identical numerics.
// R5 lesson: no-LDS register-direct staging lets the compiler sink loads
// to their use (VGPR 124 proved the prefetch set was dropped) -> 17% util.

#define N_PTS 131072
#define K_CL  2048
#define D_DIM 512
#define BM 128
#define BN 128
#define BK 32
#define NKT (K_CL / BN)    // 16 K-tiles
#define NDT (D_DIM / BK)   // 16 D-steps
#define NT  (NKT * NDT)    // 256 total iterations

typedef _Float16 half8  __attribute__((ext_vector_type(8)));
typedef _Float16 half4v __attribute__((ext_vector_type(4)));
typedef float    floatx4 __attribute__((ext_vector_type(4)));

// async global->LDS, 16B per lane; LDS dest = wave-uniform base + lane*16,
// global source address is PER-LANE (carries the swizzle).
#define GLL(g, l) __builtin_amdgcn_global_load_lds( \
    (__attribute__((address_space(1))) void*)(g),   \
    (__attribute__((address_space(3))) void*)(l), 16, 0, 0)

// ---- c2 norms: one wave per row ----
__global__ void row_norms_kernel(const float* __restrict__ A,
                                 float* __restrict__ out, int rows) {
    int gid  = blockIdx.x * blockDim.x + threadIdx.x;
    int wave = gid >> 6;
    int lane = gid & 63;
    if (wave >= rows) return;
    const float4* a = (const float4*)(A + (size_t)wave * D_DIM);
    float4 p = a[lane];
    float4 q = a[lane + 64];
    float s = p.x*p.x + p.y*p.y + p.z*p.z + p.w*p.w
            + q.x*q.x + q.y*q.y + q.z*q.z + q.w*q.w;
    #pragma unroll
    for (int off = 32; off > 0; off >>= 1) s += __shfl_down(s, off, 64);
    if (lane == 0) out[wave] = s;
}

// ---- fp32 -> (hi,lo) fp16 planes ----
__global__ void conv_f16x2_kernel(const float* __restrict__ src,
                                  _Float16* __restrict__ hi,
                                  _Float16* __restrict__ lo, int n4) {
    int i = blockIdx.x * blockDim.x + threadIdx.x;
    if (i >= n4) return;
    float4 v = ((const float4*)src)[i];
    half4v h, l;
    h.x = (_Float16)v.x; h.y = (_Float16)v.y;
    h.z = (_Float16)v.z; h.w = (_Float16)v.w;
    l.x = (_Float16)(v.x - (float)h.x);
    l.y = (_Float16)(v.y - (float)h.y);
    l.z = (_Float16)(v.z - (float)h.z);
    l.w = (_Float16)(v.w - (float)h.w);
    *(half4v*)(hi + (size_t)i * 4) = h;
    *(half4v*)(lo + (size_t)i * 4) = l;
}

// ---- main: 128x128 block over all K, split-fp16 MFMA, fused argmin ----
// LDS tile swizzle: logical element [row][k], 16B chunk j = k/8 (0..3),
// stored at chunk position j ^ ((row>>1)&3). Staging pre-swizzles the
// GLOBAL source chunk (global_load_lds writes linearly); reads use swizzled
// chunk position. Fragment ds_read_b128 => 2-way bank access (free).
template<bool XPRE, bool CPRE>
__global__ __launch_bounds__(256, 2)
void kmeans_mfma(const float* __restrict__ X, const float* __restrict__ C,
                 const _Float16* __restrict__ Xhi, const _Float16* __restrict__ Xlo,
                 const _Float16* __restrict__ Chi, const _Float16* __restrict__ Clo,
                 const float* __restrict__ c2g, int* __restrict__ out) {
    constexpr bool ASYNC = XPRE && CPRE;   // pure global_load_lds staging
    constexpr int  NB    = ASYNC ? 3 : 2;  // LDS buffers

    // unpadded [row][BK] f16 tiles (64B rows; linear dest for global_load_lds)
    __shared__ __align__(16) _Float16 sXh[NB][BM * BK], sXl[NB][BM * BK];
    __shared__ __align__(16) _Float16 sCh[NB][BN * BK], sCl[NB][BN * BK];
    __shared__ float c2s[CPRE ? 1 : K_CL];   // only the no-ws path computes c2
    __shared__ float x2s[BM];

    const int tid  = threadIdx.x;
    const int lane = tid & 63;
    const int w    = tid >> 6;       // wave id 0..3
    const int wti  = w >> 1;         // row half
    const int wtj  = w & 1;          // col half
    const int q    = lane >> 4;      // quad
    const int m16  = lane & 15;
    const int rowBase = blockIdx.x * BM;

    // swizzle constants
    const int jsrc = (((lane & 3) ^ ((lane >> 3) & 3)) * 8);  // staging: src chunk for lane
    const int swq8 = ((q ^ ((m16 >> 1) & 3)) * 8);            // read: chunk position of logical chunk q

    // c2 (no-ws fallback only; real path reads c2g straight from global)
    if constexpr (!CPRE) {
        for (int k = tid; k < K_CL; k += 256) {
            const float4* cp = (const float4*)(C + (size_t)k * D_DIM);
            float s0 = 0.f, s1 = 0.f;
            for (int j = 0; j < D_DIM / 4; j += 2) {
                float4 a = cp[j], b = cp[j + 1];
                s0 += a.x*a.x + a.y*a.y + a.z*a.z + a.w*a.w;
                s1 += b.x*b.x + b.y*b.y + b.z*b.z + b.w*b.w;
            }
            c2s[k] = s0 + s1;
        }
    }
    // x2 into LDS (2 threads per row; partials staged in sXh scratch)
    {
        int r = tid & 127, h = tid >> 7;
        const float4* xp = (const float4*)(X + (size_t)(rowBase + r) * D_DIM + h * 256);
        float s0 = 0.f, s1 = 0.f;
        for (int j = 0; j < 64; j += 2) {
            float4 a = xp[j], b = xp[j + 1];
            s0 += a.x*a.x + a.y*a.y + a.z*a.z + a.w*a.w;
            s1 += b.x*b.x + b.y*b.y + b.z*b.z + b.w*b.w;
        }
        ((float*)sXh)[tid] = s0 + s1;
    }
    __syncthreads();
    if (tid < BM) x2s[tid] = ((float*)sXh)[tid] + ((float*)sXh)[tid + 128];
    __syncthreads();   // scratch reads done before staging overwrites buf0

    // on-the-fly staging mapping (fallback paths)
    const int s_c4 = tid & 7;    // float4-col within BK
    const int s_r0 = tid >> 3;   // row 0..31

    // stage tile t (t = kt*NDT + dt) into buffer b
    auto stage = [&](int t, int b) {
        const int dtl = t & (NDT - 1);
        const int ktl = t >> 4;              // NDT == 16
        const int d0  = dtl * BK;
        const int k0l = ktl * BN;
        _Float16* dXh = sXh[b]; _Float16* dXl = sXl[b];
        _Float16* dCh = sCh[b]; _Float16* dCl = sCl[b];
        if constexpr (XPRE) {
            #pragma unroll
            for (int s = 0; s < 2; ++s) {
                const int cc = w * 2 + s;                // 16-row chunk
                const int r  = cc * 16 + (lane >> 2);
                const size_t go = (size_t)(rowBase + r) * D_DIM + d0 + jsrc;
                GLL(Xhi + go, &dXh[cc * 512]);
                GLL(Xlo + go, &dXl[cc * 512]);
            }
        } else {
            #pragma unroll
            for (int p = 0; p < 4; ++p) {
                const int r = s_r0 + p * 32;
                float4 v = *(const float4*)&X[(size_t)(rowBase + r) * D_DIM + d0 + s_c4 * 4];
                half4v h, l;
                h.x = (_Float16)v.x; h.y = (_Float16)v.y;
                h.z = (_Float16)v.z; h.w = (_Float16)v.w;
                l.x = (_Float16)(v.x - (float)h.x);
                l.y = (_Float16)(v.y - (float)h.y);
                l.z = (_Float16)(v.z - (float)h.z);
                l.w = (_Float16)(v.w - (float)h.w);
                const int off = r * BK + (((s_c4 >> 1) ^ ((r >> 1) & 3)) * 8) + (s_c4 & 1) * 4;
                *(half4v*)&dXh[off] = h;
                *(half4v*)&dXl[off] = l;
            }
        }
        if constexpr (CPRE) {
            #pragma unroll
            for (int s = 0; s < 2; ++s) {
                const int cc = w * 2 + s;
                const int r  = cc * 16 + (lane >> 2);
                const size_t go = (size_t)(k0l + r) * D_DIM + d0 + jsrc;
                GLL(Chi + go, &dCh[cc * 512]);
                GLL(Clo + go, &dCl[cc * 512]);
            }
        } else {
            #pragma unroll
            for (int p = 0; p < 4; ++p) {
                const int r = s_r0 + p * 32;
                float4 v = *(const float4*)&C[(size_t)(k0l + r) * D_DIM + d0 + s_c4 * 4];
                half4v h, l;
                h.x = (_Float16)v.x; h.y = (_Float16)v.y;
                h.z = (_Float16)v.z; h.w = (_Float16)v.w;
                l.x = (_Float16)(v.x - (float)h.x);
                l.y = (_Float16)(v.y - (float)h.y);
                l.z = (_Float16)(v.z - (float)h.z);
                l.w = (_Float16)(v.w - (float)h.w);
                const int off = r * BK + (((s_c4 >> 1) ^ ((r >> 1) & 3)) * 8) + (s_c4 & 1) * 4;
                *(half4v*)&dCh[off] = h;
                *(half4v*)&dCl[off] = l;
            }
        }
    };

    float bestV[4][4];
    int   bestI[4][4];
    #pragma unroll
    for (int ti = 0; ti < 4; ++ti)
        #pragma unroll
        for (int r = 0; r < 4; ++r) { bestV[ti][r] = 3.4e38f; bestI[ti][r] = 0; }

    int bR = 0, bS = 2;   // read buffer for tile t; stage buffer for tile t+2
    if constexpr (ASYNC) {
        // prologue: tiles 0,1 staged; need tile 0 complete to start.
        stage(0, 0);
        stage(1, 1);
        asm volatile("s_waitcnt vmcnt(8)" ::: "memory");  // stage(0) landed (self)
        __builtin_amdgcn_s_barrier();                     // ... across all waves
    }

    #pragma unroll 1
    for (int kt = 0; kt < NKT; ++kt) {
        const int k0 = kt * BN;
        floatx4 acc[4][4];
        #pragma unroll
        for (int ti = 0; ti < 4; ++ti)
            #pragma unroll
            for (int tj = 0; tj < 4; ++tj) acc[ti][tj] = (floatx4){0.f, 0.f, 0.f, 0.f};

        half8 ah[4], al[4], bh[4], bl[4];
        #define CELL(ti, tj) do {                                              \
            floatx4 a_ = acc[ti][tj];                                          \
            a_ = __builtin_amdgcn_mfma_f32_16x16x32_f16(ah[ti], bh[tj], a_, 0, 0, 0); \
            a_ = __builtin_amdgcn_mfma_f32_16x16x32_f16(ah[ti], bl[tj], a_, 0, 0, 0); \
            a_ = __builtin_amdgcn_mfma_f32_16x16x32_f16(al[ti], bh[tj], a_, 0, 0, 0); \
            acc[ti][tj] = a_;                                                  \
        } while (0)

        if constexpr (ASYNC) {
            #pragma unroll 2
            for (int dt = 0; dt < NDT; ++dt) {
                const int t = kt * NDT + dt;
                const _Float16* bXh = sXh[bR]; const _Float16* bXl = sXl[bR];
                const _Float16* bCh = sCh[bR]; const _Float16* bCl = sCl[bR];

                // fragment reads (compiler tracks lgkm deps into the MFMAs)
                #pragma unroll
                for (int ti = 0; ti < 4; ++ti) {
                    const int row = wti * 64 + ti * 16 + m16;
                    ah[ti] = *(const half8*)&bXh[row * BK + swq8];
                    al[ti] = *(const half8*)&bXl[row * BK + swq8];
                }
                #pragma unroll
                for (int tj = 0; tj < 4; ++tj) {
                    const int col = wtj * 64 + tj * 16 + m16;
                    bh[tj] = *(const half8*)&bCh[col * BK + swq8];
                    bl[tj] = *(const half8*)&bCl[col * BK + swq8];
                }

                // prefetch t+2 into the third buffer (disjoint from read +
                // resident buffers; its last readers finished at iter t-1,
                // ordered by that iter's closing barrier)
                if (t + 2 < NT) stage(t + 2, bS);

                __builtin_amdgcn_s_setprio(1);
                #pragma unroll
                for (int tj = 0; tj < 4; ++tj)
                    #pragma unroll
                    for (int ti = 0; ti < 4; ++ti) CELL(ti, tj);
                __builtin_amdgcn_s_setprio(0);

                // counted wait: retires this wave's stage(t+1) GLLs (only
                // t+2's 8 remain in flight) -> after the barrier every
                // wave's tile t+1 is resident. Never drain mid-loop.
                if (t + 2 < NT) asm volatile("s_waitcnt vmcnt(8)" ::: "memory");
                else            asm volatile("s_waitcnt vmcnt(0)" ::: "memory");
                __builtin_amdgcn_s_barrier();
                bR = (bR == NB - 1) ? 0 : bR + 1;
                bS = (bS == NB - 1) ? 0 : bS + 1;
            }
        } else {
            #pragma unroll 1
            for (int dt = 0; dt < NDT; ++dt) {
                const int t = kt * NDT + dt;
                __syncthreads();           // previous tile reads done
                stage(t, 0);
                __syncthreads();           // tile staged (drains vm+lgkm)
                #pragma unroll
                for (int ti = 0; ti < 4; ++ti) {
                    const int row = wti * 64 + ti * 16 + m16;
                    ah[ti] = *(const half8*)&sXh[0][row * BK + swq8];
                    al[ti] = *(const half8*)&sXl[0][row * BK + swq8];
                }
                #pragma unroll
                for (int tj = 0; tj < 4; ++tj) {
                    const int col = wtj * 64 + tj * 16 + m16;
                    bh[tj] = *(const half8*)&sCh[0][col * BK + swq8];
                    bl[tj] = *(const half8*)&sCl[0][col * BK + swq8];
                }
                #pragma unroll
                for (int tj = 0; tj < 4; ++tj)
                    #pragma unroll
                    for (int ti = 0; ti < 4; ++ti) CELL(ti, tj);
            }
        }
        #undef CELL

        // fused argmin epilogue. D layout: col=lane&15, row=quad*4+reg.
        // cols ascend (kt, then tj) per (ti,reg) + strict '<'  => first-occurrence.
        #pragma unroll
        for (int tj = 0; tj < 4; ++tj) {
            int col = k0 + wtj * 64 + tj * 16 + m16;
            float cv = CPRE ? c2g[col] : c2s[col];   // global: L1/L2-cached
            #pragma unroll
            for (int ti = 0; ti < 4; ++ti)
                #pragma unroll
                for (int r = 0; r < 4; ++r) {
                    float s = x2s[wti * 64 + ti * 16 + q * 4 + r] + cv;
                    float v = s - 2.0f * acc[ti][tj][r];
                    if (v < bestV[ti][r]) { bestV[ti][r] = v; bestI[ti][r] = col; }
                }
        }
    }

    // cross-lane reduce over the 16 lanes sharing each row (lexicographic)
    #pragma unroll
    for (int ti = 0; ti < 4; ++ti)
        #pragma unroll
        for (int r = 0; r < 4; ++r) {
            float v = bestV[ti][r]; int ix = bestI[ti][r];
            #pragma unroll
            for (int off = 1; off < 16; off <<= 1) {
                float ov = __shfl_xor(v, off, 64);
                int   oi = __shfl_xor(ix, off, 64);
                if (ov < v || (ov == v && oi < ix)) { v = ov; ix = oi; }
            }
            bestV[ti][r] = v; bestI[ti][r] = ix;
        }

    __syncthreads();                   // tiles no longer needed; reuse as scratch
    float* rv  = (float*)sXh;          // [128][2]
    int*   rix = (int*)sCh;            // [128][2]
    if (m16 == 0) {
        #pragma unroll
        for (int ti = 0; ti < 4; ++ti)
            #pragma unroll
            for (int r = 0; r < 4; ++r) {
                int rloc = wti * 64 + ti * 16 + q * 4 + r;
                rv[rloc * 2 + wtj]  = bestV[ti][r];
                rix[rloc * 2 + wtj] = bestI[ti][r];
            }
    }
    __syncthreads();
    if (tid < BM) {
        float v0 = rv[tid * 2], v1 = rv[tid * 2 + 1];
        int   i0 = rix[tid * 2], i1 = rix[tid * 2 + 1];
        out[rowBase + tid] = (v1 < v0 || (v1 == v0 && i1 < i0)) ? i1 : i0;
    }
}

extern "C" void kernel_launch(void* const* d_in, const int* in_sizes, int n_in,
                              void* d_out, int out_size, void* d_ws, size_t ws_size,
                              hipStream_t stream) {
    const float* X = (const float*)d_in[0];   // [N, D]
    const float* C = (const float*)d_in[1];   // [K, D]
    int* out = (int*)d_out;

    char* ws = (char*)d_ws;
    const size_t c2_off  = 0;
    const size_t chi_off = (size_t)K_CL * 4;                       // 8 KB
    const size_t clo_off = chi_off + (size_t)K_CL * D_DIM * 2;     // +2 MB
    const size_t xhi_off = clo_off + (size_t)K_CL * D_DIM * 2;     // +2 MB
    const size_t xlo_off = xhi_off + (size_t)N_PTS * D_DIM * 2;    // +128 MB
    const size_t need_C    = xhi_off;                              // ~4.2 MB
    const size_t need_full = xlo_off + (size_t)N_PTS * D_DIM * 2;  // ~272.6 MB

    if (ws_size >= need_full) {
        float*    c2  = (float*)(ws + c2_off);
        _Float16* Chi = (_Float16*)(ws + chi_off);
        _Float16* Clo = (_Float16*)(ws + clo_off);
        _Float16* Xhi = (_Float16*)(ws + xhi_off);
        _Float16* Xlo = (_Float16*)(ws + xlo_off);
        row_norms_kernel<<<(K_CL * 64) / 256, 256, 0, stream>>>(C, c2, K_CL);
        conv_f16x2_kernel<<<(K_CL * D_DIM / 4) / 256, 256, 0, stream>>>(
            C, Chi, Clo, K_CL * D_DIM / 4);
        conv_f16x2_kernel<<<(N_PTS * D_DIM / 4 + 255) / 256, 256, 0, stream>>>(
            X, Xhi, Xlo, N_PTS * D_DIM / 4);
        kmeans_mfma<true, true><<<N_PTS / BM, 256, 0, stream>>>(
            X, C, Xhi, Xlo, Chi, Clo, c2, out);
    } else if (ws_size >= need_C) {
        float*    c2  = (float*)(ws + c2_off);
        _Float16* Chi = (_Float16*)(ws + chi_off);
        _Float16* Clo = (_Float16*)(ws + clo_off);
        row_norms_kernel<<<(K_CL * 64) / 256, 256, 0, stream>>>(C, c2, K_CL);
        conv_f16x2_kernel<<<(K_CL * D_DIM / 4) / 256, 256, 0, stream>>>(
            C, Chi, Clo, K_CL * D_DIM / 4);
        kmeans_mfma<false, true><<<N_PTS / BM, 256, 0, stream>>>(
            X, C, nullptr, nullptr, Chi, Clo, c2, out);
    } else {
        kmeans_mfma<false, false><<<N_PTS / BM, 256, 0, stream>>>(
            X, C, nullptr, nullptr, nullptr, nullptr, nullptr, out);
    }
}